// Round 2
// baseline (225.900 us; speedup 1.0000x reference)
//
#include <hip/hip_runtime.h>

// N=16384 rows, E=512, V=50257, NR=100 noise words (shared), loss = mean over rows of
//   softplus(-x_t) + sum_j softplus(x_nj),  x = score + bias - log V - lpn - log NR
//
// Structure: 512 blocks x 256 threads. Each block owns 32 rows. Each of the 4 waves
// computes ALL output tiles for a K-slice of 128 (k-split), loading MFMA fragments
// directly from global memory into registers (no LDS staging, no barriers in the main
// loop). Partial accumulators are combined via ds_add at the end.

#define E_SZ   512
#define NROWS  16384
#define NRn    100
#define MT     32          // rows per block
#define KW     128         // K per wave (E/4 waves)

typedef __attribute__((ext_vector_type(8))) short short8;
typedef __attribute__((ext_vector_type(4))) float f32x4;

__device__ __forceinline__ unsigned int pack2(float a, float b) {
    // two f32 -> packed bf16 pair (round-half-up), 3 VALU
    unsigned int ua = __float_as_uint(a) + 0x8000u;
    unsigned int ub = __float_as_uint(b) + 0x8000u;
    return __builtin_amdgcn_perm(ub, ua, 0x07060302u); // [ua.b2,ua.b3,ub.b2,ub.b3]
}
__device__ __forceinline__ short8 cvt8(float4 x0, float4 x1) {
    union { unsigned int u[4]; short8 s; } r;
    r.u[0] = pack2(x0.x, x0.y);
    r.u[1] = pack2(x0.z, x0.w);
    r.u[2] = pack2(x1.x, x1.y);
    r.u[3] = pack2(x1.z, x1.w);
    return r.s;
}
__device__ __forceinline__ float softplus(float x) {
    return fmaxf(x, 0.f) + log1pf(__expf(-fabsf(x)));
}

__global__ __launch_bounds__(256, 2)
void nce_loss_kernel(const float* __restrict__ inp,   // (N, E)
                     const float* __restrict__ emb,   // (V, E)
                     const float* __restrict__ bias,  // (V,)
                     const float* __restrict__ lpn,   // (V,)
                     const int*   __restrict__ target,// (N,)
                     const int*   __restrict__ nidx,  // (NR,)
                     float* __restrict__ out)
{
    const float NTL = 15.430077572997398f;  // log(V) + log(NR)

    const int t    = threadIdx.x;
    const int w    = t >> 6;
    const int lane = t & 63;
    const int c    = lane & 15;
    const int q    = lane >> 4;
    const int r0   = blockIdx.x * MT;

    // 16 tiles x 4 regs x 64 lanes combine buffer (16 KB)
    __shared__ float sAcc[16 * 4 * 64];
    __shared__ float sBn[112];
    __shared__ float sTb[32];
    __shared__ float sWs[4];

    for (int i = t; i < 4096; i += 256) sAcc[i] = 0.f;
    if (t < 112) {
        int idx = (t < NRn) ? nidx[t] : 0;
        sBn[t] = (t < NRn) ? (bias[idx] - NTL - lpn[idx]) : 0.f;
    }
    if (t < 32) {
        int tg = target[r0 + t];
        sTb[t] = bias[tg] - NTL - lpn[tg];
    }

    // ---- per-lane fragment base pointers ----
    const float* pA0 = inp + (size_t)(r0 + c) * E_SZ;
    const float* pA1 = inp + (size_t)(r0 + 16 + c) * E_SZ;
    const float* pT0 = emb + (size_t)target[r0 + c] * E_SZ;
    const float* pT1 = emb + (size_t)target[r0 + 16 + c] * E_SZ;
    const float* pN[7];
#pragma unroll
    for (int ti = 0; ti < 7; ++ti) {
        int wd = ti * 16 + c;
        int ix = (wd < NRn) ? nidx[wd] : 0;   // clamped lanes masked in epilogue
        pN[ti] = emb + (size_t)ix * E_SZ;
    }

    f32x4 accN[2][7];
    f32x4 accT[2];
#pragma unroll
    for (int mt = 0; mt < 2; ++mt) {
        accT[mt] = {0.f, 0.f, 0.f, 0.f};
#pragma unroll
        for (int ti = 0; ti < 7; ++ti) accN[mt][ti] = {0.f, 0.f, 0.f, 0.f};
    }

    const int kbase = w * KW + q * 8;   // A/B fragment: [idx=lane&15][k=q*8+j]

    // ---- main loop: 4 k-steps of K=32, all loads direct global->reg, no barriers ----
#pragma unroll
    for (int ks = 0; ks < KW / 32; ++ks) {
        const int k = kbase + ks * 32;
        short8 A0 = cvt8(*(const float4*)(pA0 + k), *(const float4*)(pA0 + k + 4));
        short8 A1 = cvt8(*(const float4*)(pA1 + k), *(const float4*)(pA1 + k + 4));
        short8 T0 = cvt8(*(const float4*)(pT0 + k), *(const float4*)(pT0 + k + 4));
        short8 T1 = cvt8(*(const float4*)(pT1 + k), *(const float4*)(pT1 + k + 4));
        accT[0] = __builtin_amdgcn_mfma_f32_16x16x32_bf16(A0, T0, accT[0], 0, 0, 0);
        accT[1] = __builtin_amdgcn_mfma_f32_16x16x32_bf16(A1, T1, accT[1], 0, 0, 0);
#pragma unroll
        for (int ti = 0; ti < 7; ++ti) {
            short8 Bv = cvt8(*(const float4*)(pN[ti] + k), *(const float4*)(pN[ti] + k + 4));
            accN[0][ti] = __builtin_amdgcn_mfma_f32_16x16x32_bf16(A0, Bv, accN[0][ti], 0, 0, 0);
            accN[1][ti] = __builtin_amdgcn_mfma_f32_16x16x32_bf16(A1, Bv, accN[1][ti], 0, 0, 0);
        }
    }

    // ---- combine k-split partials across the 4 waves ----
    __syncthreads();   // zero-init of sAcc complete
#pragma unroll
    for (int mt = 0; mt < 2; ++mt) {
#pragma unroll
        for (int ti = 0; ti < 7; ++ti) {
#pragma unroll
            for (int r = 0; r < 4; ++r)
                atomicAdd(&sAcc[((mt * 7 + ti) * 4 + r) * 64 + lane], accN[mt][ti][r]);
        }
#pragma unroll
        for (int r = 0; r < 4; ++r)
            atomicAdd(&sAcc[((14 + mt) * 4 + r) * 64 + lane], accT[mt][r]);
    }
    __syncthreads();

    // ---- epilogue: 256 threads x 16 slots = 4096 accumulator slots ----
    // slot = (tile*4+reg)*64 + lane ; D layout: col=lane&15, row=(lane>>4)*4+reg
    const int tr   = t >> 2;          // tile*4+reg
    const int tile = tr >> 2;
    const int reg  = tr & 3;
    const int lb   = (t & 3) * 16;    // lane group
    float ll = 0.f;
    if (tile < 14) {
        const int ti = (tile < 7) ? tile : tile - 7;
#pragma unroll
        for (int i = 0; i < 16; ++i) {
            int ln = lb + i;
            int word = ti * 16 + (ln & 15);
            if (word < NRn)
                ll += softplus(sAcc[tr * 64 + ln] + sBn[word]);
        }
    } else {
        const int mt = tile - 14;
        const int row = (lb >> 4) * 4 + reg;   // lb>>4 == quad of this lane group
#pragma unroll
        for (int i = 0; i < 16; ++i) {
            int ln = lb + i;
            if ((ln & 15) == row)              // diagonal only: D[r][r] = target score
                ll += softplus(-(sAcc[tr * 64 + ln] + sTb[mt * 16 + row]));
        }
    }

    // ---- block reduction -> single atomic ----
#pragma unroll
    for (int off = 32; off > 0; off >>= 1) ll += __shfl_down(ll, off);
    if (lane == 0) sWs[w] = ll;
    __syncthreads();
    if (t == 0) {
        float s = (sWs[0] + sWs[1]) + (sWs[2] + sWs[3]);
        atomicAdd(out, s * (1.f / (float)NROWS));
    }
}

extern "C" void kernel_launch(void* const* d_in, const int* in_sizes, int n_in,
                              void* d_out, int out_size, void* d_ws, size_t ws_size,
                              hipStream_t stream) {
    const float* inp    = (const float*)d_in[0];
    const float* emb    = (const float*)d_in[1];
    const float* bias   = (const float*)d_in[2];
    const float* lpn    = (const float*)d_in[3];
    const int*   target = (const int*)d_in[4];
    const int*   nidx   = (const int*)d_in[5];
    float* out = (float*)d_out;

    hipMemsetAsync(out, 0, sizeof(float), stream);
    nce_loss_kernel<<<NROWS / MT, 256, 0, stream>>>(inp, emb, bias, lpn, target, nidx, out);
}

// Round 3
// 188.165 us; speedup vs baseline: 1.2005x; 1.2005x over previous
//
#include <hip/hip_runtime.h>

// NCE loss, fused. N=16384 rows, E=512, V=50257, NR=100 shared noise words.
// loss = mean_rows[ softplus(-x_t) + sum_j softplus(x_nj) ],
//   x = <inp_row, emb_word> + bias_w - log V - logp_noise_w - log NR
//
// R3 structure: 1024 blocks x 256 threads. Block owns 16 rows; its 4 waves
// k-split E=512 into K=128 slices. Each wave computes 7 noise tiles + 1
// target tile (diagonal) of 16x16x32 bf16 MFMA, loading fragments directly
// global->reg with a software pipeline: cvt of step ks overlaps the in-flight
// loads of step ks+1. Per-wave partials combine via disjoint LDS slabs.

#define E_SZ   512
#define NROWS  16384
#define NRn    100
#define MT     16          // rows per block
#define NBLK   (NROWS / MT)

typedef __attribute__((ext_vector_type(8))) short short8;
typedef __attribute__((ext_vector_type(4))) float f32x4;

__device__ __forceinline__ unsigned int pack2(float a, float b) {
    unsigned int ua = __float_as_uint(a) + 0x8000u;
    unsigned int ub = __float_as_uint(b) + 0x8000u;
    return __builtin_amdgcn_perm(ub, ua, 0x07060302u);
}
__device__ __forceinline__ short8 cvt8(float4 x0, float4 x1) {
    union { unsigned int u[4]; short8 s; } r;
    r.u[0] = pack2(x0.x, x0.y);
    r.u[1] = pack2(x0.z, x0.w);
    r.u[2] = pack2(x1.x, x1.y);
    r.u[3] = pack2(x1.z, x1.w);
    return r.s;
}
__device__ __forceinline__ float softplus(float x) {
    return fmaxf(x, 0.f) + log1pf(__expf(-fabsf(x)));
}

__global__ __launch_bounds__(256, 3)
void nce_loss_kernel(const float* __restrict__ inp,   // (N, E)
                     const float* __restrict__ emb,   // (V, E)
                     const float* __restrict__ bias,  // (V,)
                     const float* __restrict__ lpn,   // (V,)
                     const int*   __restrict__ target,// (N,)
                     const int*   __restrict__ nidx,  // (NR,)
                     float* __restrict__ out)
{
    const float NTL = 15.430077572997398f;  // log(V) + log(NR)

    const int t    = threadIdx.x;
    const int w    = t >> 6;
    const int lane = t & 63;
    const int c    = lane & 15;
    const int q    = lane >> 4;
    const int r0   = blockIdx.x * MT;

    // per-wave disjoint combine slabs: 4 x (8 tiles x 4 regs x 64 lanes)
    __shared__ float sAcc[4 * 2048];   // 32 KB
    __shared__ float sBn[112];
    __shared__ float sTb[MT];
    __shared__ float sWs[4];

    if (t < 112) {
        int idx = (t < NRn) ? nidx[t] : 0;
        sBn[t] = (t < NRn) ? (bias[idx] - NTL - lpn[idx]) : 0.f;
    }
    if (t < MT) {
        int tg = target[r0 + t];
        sTb[t] = bias[tg] - NTL - lpn[tg];
    }

    // ---- per-lane fragment base pointers (A/B layout: [idx=lane&15][k=q*8+j]) ----
    const float* pA = inp + (size_t)(r0 + c) * E_SZ;
    const float* pT = emb + (size_t)target[r0 + c] * E_SZ;
    const float* pN[7];
#pragma unroll
    for (int ti = 0; ti < 7; ++ti) {
        int wd = ti * 16 + c;
        int ix = (wd < NRn) ? nidx[wd] : 0;   // clamped lanes masked in epilogue
        pN[ti] = emb + (size_t)ix * E_SZ;
    }

    f32x4 accN[7];
    f32x4 accT = {0.f, 0.f, 0.f, 0.f};
#pragma unroll
    for (int ti = 0; ti < 7; ++ti) accN[ti] = {0.f, 0.f, 0.f, 0.f};

    const int kb = w * 128 + q * 8;   // this wave's K-slice + lane k-offset

#define LOADSTEP(K)                                              \
    {                                                            \
        cur[0][0] = *(const float4*)(pA + (K));                  \
        cur[0][1] = *(const float4*)(pA + (K) + 4);              \
        cur[1][0] = *(const float4*)(pT + (K));                  \
        cur[1][1] = *(const float4*)(pT + (K) + 4);              \
        _Pragma("unroll")                                        \
        for (int ti = 0; ti < 7; ++ti) {                         \
            cur[2 + ti][0] = *(const float4*)(pN[ti] + (K));     \
            cur[2 + ti][1] = *(const float4*)(pN[ti] + (K) + 4); \
        }                                                        \
    }

    float4 cur[9][2];
    LOADSTEP(kb);                       // prologue: k-step 0 in flight

#pragma unroll
    for (int ks = 0; ks < 4; ++ks) {
        // consume in-flight loads: f32 -> bf16 fragments (frees cur regs)
        short8 A = cvt8(cur[0][0], cur[0][1]);
        short8 T = cvt8(cur[1][0], cur[1][1]);
        short8 Bv[7];
#pragma unroll
        for (int ti = 0; ti < 7; ++ti)
            Bv[ti] = cvt8(cur[2 + ti][0], cur[2 + ti][1]);

        // issue next step's 18 loads before the MFMAs
        if (ks < 3) LOADSTEP(kb + (ks + 1) * 32);

        accT = __builtin_amdgcn_mfma_f32_16x16x32_bf16(A, T, accT, 0, 0, 0);
#pragma unroll
        for (int ti = 0; ti < 7; ++ti)
            accN[ti] = __builtin_amdgcn_mfma_f32_16x16x32_bf16(A, Bv[ti], accN[ti], 0, 0, 0);
    }
#undef LOADSTEP

    // ---- combine k-split partials: disjoint slabs, no atomics ----
    float* slab = sAcc + w * 2048;      // slot = tile*256 + reg*64 + lane
#pragma unroll
    for (int ti = 0; ti < 7; ++ti)
#pragma unroll
        for (int r = 0; r < 4; ++r)
            slab[ti * 256 + r * 64 + lane] = accN[ti][r];
#pragma unroll
    for (int r = 0; r < 4; ++r)
        slab[7 * 256 + r * 64 + lane] = accT[r];
    __syncthreads();

    // ---- epilogue: thread t handles slot (tile=i, reg=t>>6, lane=t&63) per tile i ----
    // C/D layout: col(word/row-idx)=lane&15, row=(lane>>4)*4+reg
    const int ereg = w;                // (t>>6)&3
    const int col  = lane & 15;
    const int erow = (lane >> 4) * 4 + ereg;
    float ll = 0.f;
#pragma unroll
    for (int i = 0; i < 7; ++i) {
        int word = i * 16 + col;
        float v = sAcc[i * 256 + t] + sAcc[2048 + i * 256 + t]
                + sAcc[4096 + i * 256 + t] + sAcc[6144 + i * 256 + t];
        if (word < NRn)
            ll += softplus(v + sBn[word]);
    }
    {   // target tile: diagonal only
        float v = sAcc[7 * 256 + t] + sAcc[2048 + 7 * 256 + t]
                + sAcc[4096 + 7 * 256 + t] + sAcc[6144 + 7 * 256 + t];
        if (col == erow)
            ll += softplus(-(v + sTb[erow]));
    }

    // ---- block reduction -> single global atomic ----
#pragma unroll
    for (int off = 32; off > 0; off >>= 1) ll += __shfl_down(ll, off);
    if (lane == 0) sWs[w] = ll;
    __syncthreads();
    if (t == 0) {
        float s = (sWs[0] + sWs[1]) + (sWs[2] + sWs[3]);
        atomicAdd(out, s * (1.f / (float)NROWS));
    }
}

extern "C" void kernel_launch(void* const* d_in, const int* in_sizes, int n_in,
                              void* d_out, int out_size, void* d_ws, size_t ws_size,
                              hipStream_t stream) {
    const float* inp    = (const float*)d_in[0];
    const float* emb    = (const float*)d_in[1];
    const float* bias   = (const float*)d_in[2];
    const float* lpn    = (const float*)d_in[3];
    const int*   target = (const int*)d_in[4];
    const int*   nidx   = (const int*)d_in[5];
    float* out = (float*)d_out;

    hipMemsetAsync(out, 0, sizeof(float), stream);
    nce_loss_kernel<<<NBLK, 256, 0, stream>>>(inp, emb, bias, lpn, target, nidx, out);
}

// Round 4
// 184.959 us; speedup vs baseline: 1.2214x; 1.0173x over previous
//
#include <hip/hip_runtime.h>

// NCE loss, fused. N=16384 rows, E=512, V=50257, NR=100 shared noise words.
// loss = mean_rows[ softplus(-x_t) + sum_j softplus(x_nj) ],
//   x = <inp_row, emb_word> + bias_w - log V - logp_noise_w - log NR
//
// R4: two kernels.
//  1) prep_noise: gather+convert the 100 noise rows to bf16 ONCE into d_ws
//     (112x512 bf16, B-fragment-ready) + per-word bias constants. ~100 KB.
//  2) main: 1024 blocks x 256 threads, 16 rows/block, 4-way K-split.
//     Per k-step a wave issues 4 f32 float4 loads (A,T) + 7 bf16 16B loads (B)
//     -- 11 vmem instrs vs 18 -- and converts only A,T. All 1024 blocks
//     resident at __launch_bounds__(256,4).

#define E_SZ   512
#define NROWS  16384
#define NRn    100
#define NWp    112
#define MT     16
#define NBLK   (NROWS / MT)

typedef __attribute__((ext_vector_type(8))) short short8;
typedef __attribute__((ext_vector_type(4))) float f32x4;

#define NTL 15.430077572997398f   // log(V) + log(NR)

__device__ __forceinline__ unsigned int pack2(float a, float b) {
    unsigned int ua = __float_as_uint(a) + 0x8000u;
    unsigned int ub = __float_as_uint(b) + 0x8000u;
    return __builtin_amdgcn_perm(ub, ua, 0x07060302u); // [ua.b2,ua.b3,ub.b2,ub.b3]
}
__device__ __forceinline__ short8 cvt8(float4 x0, float4 x1) {
    union { unsigned int u[4]; short8 s; } r;
    r.u[0] = pack2(x0.x, x0.y);
    r.u[1] = pack2(x0.z, x0.w);
    r.u[2] = pack2(x1.x, x1.y);
    r.u[3] = pack2(x1.z, x1.w);
    return r.s;
}
__device__ __forceinline__ float softplus(float x) {
    return fmaxf(x, 0.f) + log1pf(__expf(-fabsf(x)));
}

// ---- kernel 1: noise rows f32 -> bf16 into ws, plus per-word constants ----
__global__ __launch_bounds__(128)
void prep_noise(const float* __restrict__ emb, const float* __restrict__ bias,
                const float* __restrict__ lpn, const int* __restrict__ nidx,
                unsigned short* __restrict__ nB,   // (112, 512) bf16
                float* __restrict__ nBn)           // (112,)
{
    const int j = blockIdx.x;          // word slot 0..111
    const int t = threadIdx.x;         // 0..127, 4 elems each
    const int idx = (j < NRn) ? nidx[j] : 0;
    float4 v = {0.f, 0.f, 0.f, 0.f};
    if (j < NRn) v = *(const float4*)(emb + (size_t)idx * E_SZ + t * 4);
    union { unsigned int u[2]; } r;
    r.u[0] = pack2(v.x, v.y);
    r.u[1] = pack2(v.z, v.w);
    *(uint2*)(nB + (size_t)j * E_SZ + t * 4) = make_uint2(r.u[0], r.u[1]);
    if (t == 0)
        nBn[j] = (j < NRn) ? (bias[idx] - NTL - lpn[idx]) : 0.f;
}

// ---- kernel 2: fused scores + softplus + reduction ----
__global__ __launch_bounds__(256, 4)
void nce_loss_kernel(const float* __restrict__ inp,   // (N, E)
                     const float* __restrict__ emb,   // (V, E)
                     const float* __restrict__ bias,  // (V,)
                     const float* __restrict__ lpn,   // (V,)
                     const int*   __restrict__ target,// (N,)
                     const unsigned short* __restrict__ nB,  // (112,512) bf16
                     const float* __restrict__ nBn,   // (112,)
                     float* __restrict__ out)
{
    const int t    = threadIdx.x;
    const int w    = t >> 6;
    const int lane = t & 63;
    const int c    = lane & 15;
    const int q    = lane >> 4;
    const int r0   = blockIdx.x * MT;

    __shared__ float sAcc[4 * 2048];   // per-wave disjoint combine slabs, 32 KB
    __shared__ float sBn[NWp];
    __shared__ float sTb[MT];
    __shared__ float sWs[4];

    if (t < NWp) sBn[t] = nBn[t];
    if (t < MT) {
        int tg = target[r0 + t];
        sTb[t] = bias[tg] - NTL - lpn[tg];
    }

    // fragment base pointers (A/B layout: [idx=lane&15][k=q*8+j])
    const float* pA = inp + (size_t)(r0 + c) * E_SZ;
    const float* pT = emb + (size_t)target[r0 + c] * E_SZ;
    const unsigned short* pN[7];
#pragma unroll
    for (int ti = 0; ti < 7; ++ti)
        pN[ti] = nB + (size_t)(ti * 16 + c) * E_SZ;

    f32x4 accN[7];
    f32x4 accT = {0.f, 0.f, 0.f, 0.f};
#pragma unroll
    for (int ti = 0; ti < 7; ++ti) accN[ti] = {0.f, 0.f, 0.f, 0.f};

    const int kb = w * 128 + q * 8;    // wave K-slice + lane k-offset

#define LOADSTEP(K)                                          \
    {                                                        \
        curA[0] = *(const float4*)(pA + (K));                \
        curA[1] = *(const float4*)(pA + (K) + 4);            \
        curT[0] = *(const float4*)(pT + (K));                \
        curT[1] = *(const float4*)(pT + (K) + 4);            \
        _Pragma("unroll")                                    \
        for (int ti = 0; ti < 7; ++ti)                       \
            curB[ti] = *(const short8*)(pN[ti] + (K));       \
    }

    float4 curA[2], curT[2];
    short8 curB[7];
    LOADSTEP(kb);

#pragma unroll
    for (int ks = 0; ks < 4; ++ks) {
        short8 A = cvt8(curA[0], curA[1]);
        short8 T = cvt8(curT[0], curT[1]);
        short8 Bv[7];
#pragma unroll
        for (int ti = 0; ti < 7; ++ti) Bv[ti] = curB[ti];

        if (ks < 3) LOADSTEP(kb + (ks + 1) * 32);

        accT = __builtin_amdgcn_mfma_f32_16x16x32_bf16(A, T, accT, 0, 0, 0);
#pragma unroll
        for (int ti = 0; ti < 7; ++ti)
            accN[ti] = __builtin_amdgcn_mfma_f32_16x16x32_bf16(A, Bv[ti], accN[ti], 0, 0, 0);
    }
#undef LOADSTEP

    // combine k-split partials: disjoint slabs, no atomics
    float* slab = sAcc + w * 2048;     // slot = tile*256 + reg*64 + lane
#pragma unroll
    for (int ti = 0; ti < 7; ++ti)
#pragma unroll
        for (int r = 0; r < 4; ++r)
            slab[ti * 256 + r * 64 + lane] = accN[ti][r];
#pragma unroll
    for (int r = 0; r < 4; ++r)
        slab[7 * 256 + r * 64 + lane] = accT[r];
    __syncthreads();

    // epilogue: C/D layout col=lane&15, row=(lane>>4)*4+reg
    const int ereg = w;
    const int col  = lane & 15;
    const int erow = (lane >> 4) * 4 + ereg;
    float ll = 0.f;
#pragma unroll
    for (int i = 0; i < 7; ++i) {
        int word = i * 16 + col;
        float v = sAcc[i * 256 + t] + sAcc[2048 + i * 256 + t]
                + sAcc[4096 + i * 256 + t] + sAcc[6144 + i * 256 + t];
        if (word < NRn)
            ll += softplus(v + sBn[word]);
    }
    {
        float v = sAcc[7 * 256 + t] + sAcc[2048 + 7 * 256 + t]
                + sAcc[4096 + 7 * 256 + t] + sAcc[6144 + 7 * 256 + t];
        if (col == erow)
            ll += softplus(-(v + sTb[erow]));
    }

#pragma unroll
    for (int off = 32; off > 0; off >>= 1) ll += __shfl_down(ll, off);
    if (lane == 0) sWs[w] = ll;
    __syncthreads();
    if (t == 0) {
        float s = (sWs[0] + sWs[1]) + (sWs[2] + sWs[3]);
        atomicAdd(out, s * (1.f / (float)NROWS));
    }
}

extern "C" void kernel_launch(void* const* d_in, const int* in_sizes, int n_in,
                              void* d_out, int out_size, void* d_ws, size_t ws_size,
                              hipStream_t stream) {
    const float* inp    = (const float*)d_in[0];
    const float* emb    = (const float*)d_in[1];
    const float* bias   = (const float*)d_in[2];
    const float* lpn    = (const float*)d_in[3];
    const int*   target = (const int*)d_in[4];
    const int*   nidx   = (const int*)d_in[5];
    float* out = (float*)d_out;

    unsigned short* nB  = (unsigned short*)d_ws;              // 112*512*2 = 114688 B
    float*          nBn = (float*)((char*)d_ws + (size_t)NWp * E_SZ * 2);

    hipMemsetAsync(out, 0, sizeof(float), stream);
    prep_noise<<<NWp, 128, 0, stream>>>(emb, bias, lpn, nidx, nB, nBn);
    nce_loss_kernel<<<NBLK, 256, 0, stream>>>(inp, emb, bias, lpn, target, nB, nBn, out);
}

// Round 5
// 178.431 us; speedup vs baseline: 1.2660x; 1.0366x over previous
//
#include <hip/hip_runtime.h>

// NCE loss, fused. N=16384 rows, E=512, V=50257, NR=100 shared noise words.
// loss = mean_rows[ softplus(-x_t) + sum_j softplus(x_nj) ],
//   x = <inp_row, emb_word> + bias_w - log V - logp_noise_w - log NR
//
// R5: full-depth memory-level parallelism.
//  prep_noise: noise rows f32->bf16 once into d_ws, layout [kg][word][8]
//    (kg = k>>3) so the 7 B-tile fragment loads per k-step share one base
//    pointer with 256 B immediate offsets.
//  main: 1024 blocks x 256 thr, 16 rows/block, 4-way K-split (K=128/wave).
//    ALL 16 A/T dwordx4 loads for the wave's K-slice issue up-front (64 VGPRs
//    in flight); B loads run depth-1. Per-wave exposed latency drops from
//    ~4 serialized misses to ~1.

#define E_SZ   512
#define NROWS  16384
#define NRn    100
#define NWp    112
#define MT     16
#define NBLK   (NROWS / MT)

typedef __attribute__((ext_vector_type(8))) short short8;
typedef __attribute__((ext_vector_type(4))) float f32x4;

#define NTL 15.430077572997398f   // log(V) + log(NR)

__device__ __forceinline__ unsigned int pack2(float a, float b) {
    unsigned int ua = __float_as_uint(a) + 0x8000u;
    unsigned int ub = __float_as_uint(b) + 0x8000u;
    return __builtin_amdgcn_perm(ub, ua, 0x07060302u); // [ua.b2,ua.b3,ub.b2,ub.b3]
}
__device__ __forceinline__ float softplus(float x) {
    return fmaxf(x, 0.f) + log1pf(__expf(-fabsf(x)));
}
__device__ __forceinline__ short8 cvt8(float4 x0, float4 x1) {
    union { unsigned int u[4]; short8 s; } r;
    r.u[0] = pack2(x0.x, x0.y);
    r.u[1] = pack2(x0.z, x0.w);
    r.u[2] = pack2(x1.x, x1.y);
    r.u[3] = pack2(x1.z, x1.w);
    return r.s;
}

// ---- kernel 1: noise rows f32 -> bf16, layout nB[kg][word][8], kg=k>>3 ----
__global__ __launch_bounds__(128)
void prep_noise(const float* __restrict__ emb, const float* __restrict__ bias,
                const float* __restrict__ lpn, const int* __restrict__ nidx,
                unsigned short* __restrict__ nB,   // (64, 112, 8) bf16
                float* __restrict__ nBn)           // (112,)
{
    const int j = blockIdx.x;          // word slot 0..111
    const int t = threadIdx.x;         // 0..127, elems 4t..4t+3
    const int idx = (j < NRn) ? nidx[j] : 0;
    float4 v = {0.f, 0.f, 0.f, 0.f};
    if (j < NRn) v = *(const float4*)(emb + (size_t)idx * E_SZ + t * 4);
    unsigned int u0 = pack2(v.x, v.y);
    unsigned int u1 = pack2(v.z, v.w);
    const int kg  = t >> 1;            // (4t)>>3
    const int off = (t & 1) * 4;       // (4t)&7
    *(uint2*)(nB + ((size_t)kg * NWp + j) * 8 + off) = make_uint2(u0, u1);
    if (t == 0)
        nBn[j] = (j < NRn) ? (bias[idx] - NTL - lpn[idx]) : 0.f;
}

// ---- kernel 2: fused scores + softplus + reduction ----
__global__ __launch_bounds__(256, 3)
void nce_loss_kernel(const float* __restrict__ inp,   // (N, E)
                     const float* __restrict__ emb,   // (V, E)
                     const float* __restrict__ bias,  // (V,)
                     const float* __restrict__ lpn,   // (V,)
                     const int*   __restrict__ target,// (N,)
                     const unsigned short* __restrict__ nB,  // (64,112,8) bf16
                     const float* __restrict__ nBn,   // (112,)
                     float* __restrict__ out)
{
    const int t    = threadIdx.x;
    const int w    = t >> 6;
    const int lane = t & 63;
    const int c    = lane & 15;
    const int q    = lane >> 4;
    const int r0   = blockIdx.x * MT;

    __shared__ float sAcc[4 * 2048];   // per-wave disjoint combine slabs, 32 KB
    __shared__ float sBn[NWp];
    __shared__ float sTb[MT];
    __shared__ float sWs[4];

    if (t < NWp) sBn[t] = nBn[t];
    if (t < MT) {
        int tg = target[r0 + t];
        sTb[t] = bias[tg] - NTL - lpn[tg];
    }

    // fragment pointers (A/B layout: [idx=lane&15][k=q*8+j])
    const int kb = w * 128 + q * 8;    // wave K-slice base + lane k-offset
    const float* pA = inp + (size_t)(r0 + c) * E_SZ + kb;
    const float* pT = emb + (size_t)target[r0 + c] * E_SZ + kb;
    // B base for step ks: nB + ((w*16+q + ks*4)*112 + c)*8 ; tile ti at +ti*128
    const unsigned short* pB = nB + ((size_t)(w * 16 + q) * NWp + c) * 8;

    f32x4 accN[7];
    f32x4 accT = {0.f, 0.f, 0.f, 0.f};
#pragma unroll
    for (int ti = 0; ti < 7; ++ti) accN[ti] = {0.f, 0.f, 0.f, 0.f};

    // ---- issue step-0 B loads, then ALL A/T loads (full-depth MLP) ----
    short8 curB[7];
#pragma unroll
    for (int ti = 0; ti < 7; ++ti) curB[ti] = *(const short8*)(pB + ti * 128);

    float4 a[4][2], tt[4][2];
#pragma unroll
    for (int ks = 0; ks < 4; ++ks) {
        a[ks][0]  = *(const float4*)(pA + ks * 32);
        a[ks][1]  = *(const float4*)(pA + ks * 32 + 4);
        tt[ks][0] = *(const float4*)(pT + ks * 32);
        tt[ks][1] = *(const float4*)(pT + ks * 32 + 4);
    }

#pragma unroll
    for (int ks = 0; ks < 4; ++ks) {
        short8 A = cvt8(a[ks][0], a[ks][1]);
        short8 T = cvt8(tt[ks][0], tt[ks][1]);
        short8 Bv[7];
#pragma unroll
        for (int ti = 0; ti < 7; ++ti) Bv[ti] = curB[ti];

        if (ks < 3) {
            const unsigned short* pBn = pB + (ks + 1) * 4 * NWp * 8;
#pragma unroll
            for (int ti = 0; ti < 7; ++ti)
                curB[ti] = *(const short8*)(pBn + ti * 128);
        }

        accT = __builtin_amdgcn_mfma_f32_16x16x32_bf16(A, T, accT, 0, 0, 0);
#pragma unroll
        for (int ti = 0; ti < 7; ++ti)
            accN[ti] = __builtin_amdgcn_mfma_f32_16x16x32_bf16(A, Bv[ti], accN[ti], 0, 0, 0);
    }

    // ---- combine k-split partials: disjoint slabs, no atomics ----
    float* slab = sAcc + w * 2048;     // slot = tile*256 + reg*64 + lane
#pragma unroll
    for (int ti = 0; ti < 7; ++ti)
#pragma unroll
        for (int r = 0; r < 4; ++r)
            slab[ti * 256 + r * 64 + lane] = accN[ti][r];
#pragma unroll
    for (int r = 0; r < 4; ++r)
        slab[7 * 256 + r * 64 + lane] = accT[r];
    __syncthreads();

    // ---- epilogue: C/D layout col=lane&15, row=(lane>>4)*4+reg ----
    const int ereg = w;
    const int col  = lane & 15;
    const int erow = (lane >> 4) * 4 + ereg;
    float ll = 0.f;
#pragma unroll
    for (int i = 0; i < 7; ++i) {
        int word = i * 16 + col;
        float v = sAcc[i * 256 + t] + sAcc[2048 + i * 256 + t]
                + sAcc[4096 + i * 256 + t] + sAcc[6144 + i * 256 + t];
        if (word < NRn)
            ll += softplus(v + sBn[word]);
    }
    {
        float v = sAcc[7 * 256 + t] + sAcc[2048 + 7 * 256 + t]
                + sAcc[4096 + 7 * 256 + t] + sAcc[6144 + 7 * 256 + t];
        if (col == erow)
            ll += softplus(-(v + sTb[erow]));
    }

#pragma unroll
    for (int off = 32; off > 0; off >>= 1) ll += __shfl_down(ll, off);
    if (lane == 0) sWs[w] = ll;
    __syncthreads();
    if (t == 0) {
        float s = (sWs[0] + sWs[1]) + (sWs[2] + sWs[3]);
        atomicAdd(out, s * (1.f / (float)NROWS));
    }
}

extern "C" void kernel_launch(void* const* d_in, const int* in_sizes, int n_in,
                              void* d_out, int out_size, void* d_ws, size_t ws_size,
                              hipStream_t stream) {
    const float* inp    = (const float*)d_in[0];
    const float* emb    = (const float*)d_in[1];
    const float* bias   = (const float*)d_in[2];
    const float* lpn    = (const float*)d_in[3];
    const int*   target = (const int*)d_in[4];
    const int*   nidx   = (const int*)d_in[5];
    float* out = (float*)d_out;

    unsigned short* nB  = (unsigned short*)d_ws;              // 64*112*8*2 = 114688 B
    float*          nBn = (float*)((char*)d_ws + (size_t)64 * NWp * 8 * 2);

    hipMemsetAsync(out, 0, sizeof(float), stream);
    prep_noise<<<NWp, 128, 0, stream>>>(emb, bias, lpn, nidx, nB, nBn);
    nce_loss_kernel<<<NBLK, 256, 0, stream>>>(inp, emb, bias, lpn, target, nB, nBn, out);
}

// Round 6
// 177.768 us; speedup vs baseline: 1.2708x; 1.0037x over previous
//
#include <hip/hip_runtime.h>

// NCE loss, fused. N=16384 rows, E=512, V=50257, NR=100 shared noise words.
// loss = mean_rows[ softplus(-x_t) + sum_j softplus(x_nj) ],
//   x = <inp_row, emb_word> + bias_w - log V - logp_noise_w - log NR
//
// R6: occupancy/MLP rebalance.
//  - prep_noise: noise rows f32->bf16 once into d_ws ([kg][word][8] layout),
//    per-word bias constants, and zeroes the output scalar (memset folded in).
//  - main: 1024 blocks x 256 thr, 16 rows/block, 4-way K-split (K=128/wave).
//    A/T prefetch depth 2 (was 4): 16 fewer live VGPRs x2 buffers, letting
//    __launch_bounds__(256,4) make ALL 1024 blocks resident (16 waves/CU) --
//    more outstanding gather lines chip-wide than 24-deep at 12 waves/CU.

#define E_SZ   512
#define NROWS  16384
#define NRn    100
#define NWp    112
#define MT     16
#define NBLK   (NROWS / MT)

typedef __attribute__((ext_vector_type(8))) short short8;
typedef __attribute__((ext_vector_type(4))) float f32x4;

#define NTL 15.430077572997398f   // log(V) + log(NR)

__device__ __forceinline__ unsigned int pack2(float a, float b) {
    unsigned int ua = __float_as_uint(a) + 0x8000u;
    unsigned int ub = __float_as_uint(b) + 0x8000u;
    return __builtin_amdgcn_perm(ub, ua, 0x07060302u); // [ua.b2,ua.b3,ub.b2,ub.b3]
}
__device__ __forceinline__ float softplus(float x) {
    return fmaxf(x, 0.f) + log1pf(__expf(-fabsf(x)));
}
__device__ __forceinline__ short8 cvt8(float4 x0, float4 x1) {
    union { unsigned int u[4]; short8 s; } r;
    r.u[0] = pack2(x0.x, x0.y);
    r.u[1] = pack2(x0.z, x0.w);
    r.u[2] = pack2(x1.x, x1.y);
    r.u[3] = pack2(x1.z, x1.w);
    return r.s;
}

// ---- kernel 1: noise rows f32 -> bf16 (nB[kg][word][8], kg=k>>3) + out=0 ----
__global__ __launch_bounds__(128)
void prep_noise(const float* __restrict__ emb, const float* __restrict__ bias,
                const float* __restrict__ lpn, const int* __restrict__ nidx,
                unsigned short* __restrict__ nB,   // (64, 112, 8) bf16
                float* __restrict__ nBn,           // (112,)
                float* __restrict__ out)
{
    const int j = blockIdx.x;          // word slot 0..111
    const int t = threadIdx.x;         // 0..127, elems 4t..4t+3
    const int idx = (j < NRn) ? nidx[j] : 0;
    float4 v = {0.f, 0.f, 0.f, 0.f};
    if (j < NRn) v = *(const float4*)(emb + (size_t)idx * E_SZ + t * 4);
    unsigned int u0 = pack2(v.x, v.y);
    unsigned int u1 = pack2(v.z, v.w);
    const int kg  = t >> 1;            // (4t)>>3
    const int off = (t & 1) * 4;       // (4t)&7
    *(uint2*)(nB + ((size_t)kg * NWp + j) * 8 + off) = make_uint2(u0, u1);
    if (t == 0)
        nBn[j] = (j < NRn) ? (bias[idx] - NTL - lpn[idx]) : 0.f;
    if (j == 0 && t == 0)
        out[0] = 0.f;                  // memset folded in; main kernel ordered after
}

// ---- kernel 2: fused scores + softplus + reduction ----
__global__ __launch_bounds__(256, 4)
void nce_loss_kernel(const float* __restrict__ inp,   // (N, E)
                     const float* __restrict__ emb,   // (V, E)
                     const float* __restrict__ bias,  // (V,)
                     const float* __restrict__ lpn,   // (V,)
                     const int*   __restrict__ target,// (N,)
                     const unsigned short* __restrict__ nB,  // (64,112,8) bf16
                     const float* __restrict__ nBn,   // (112,)
                     float* __restrict__ out)
{
    const int t    = threadIdx.x;
    const int w    = t >> 6;
    const int lane = t & 63;
    const int c    = lane & 15;
    const int q    = lane >> 4;
    const int r0   = blockIdx.x * MT;

    __shared__ float sAcc[4 * 2048];   // per-wave disjoint combine slabs, 32 KB
    __shared__ float sBn[NWp];
    __shared__ float sTb[MT];
    __shared__ float sWs[4];

    if (t < NWp) sBn[t] = nBn[t];
    if (t < MT) {
        int tg = target[r0 + t];
        sTb[t] = bias[tg] - NTL - lpn[tg];
    }

    // fragment pointers (A/B layout: [idx=lane&15][k=q*8+j])
    const int kb = w * 128 + q * 8;    // wave K-slice base + lane k-offset
    const float* pA = inp + (size_t)(r0 + c) * E_SZ + kb;
    const float* pT = emb + (size_t)target[r0 + c] * E_SZ + kb;
    // B base for step ks: nB + ((w*16+q + ks*4)*112 + c)*8 ; tile ti at +ti*128
    const unsigned short* pB = nB + ((size_t)(w * 16 + q) * NWp + c) * 8;

    f32x4 accN[7];
    f32x4 accT = {0.f, 0.f, 0.f, 0.f};
#pragma unroll
    for (int ti = 0; ti < 7; ++ti) accN[ti] = {0.f, 0.f, 0.f, 0.f};

    // ---- prologue: B step0; A/T steps 0 and 1 (depth-2 pipeline) ----
    short8 curB[7];
#pragma unroll
    for (int ti = 0; ti < 7; ++ti) curB[ti] = *(const short8*)(pB + ti * 128);

    float4 a[2][2], tt[2][2];
#pragma unroll
    for (int p = 0; p < 2; ++p) {
        a[p][0]  = *(const float4*)(pA + p * 32);
        a[p][1]  = *(const float4*)(pA + p * 32 + 4);
        tt[p][0] = *(const float4*)(pT + p * 32);
        tt[p][1] = *(const float4*)(pT + p * 32 + 4);
    }

#pragma unroll
    for (int ks = 0; ks < 4; ++ks) {
        const int pb = ks & 1;
        short8 A = cvt8(a[pb][0], a[pb][1]);
        short8 T = cvt8(tt[pb][0], tt[pb][1]);
        short8 Bv[7];
#pragma unroll
        for (int ti = 0; ti < 7; ++ti) Bv[ti] = curB[ti];

        // refill: A/T for step ks+2 into the buffer just consumed; B for ks+1
        if (ks < 2) {
            a[pb][0]  = *(const float4*)(pA + (ks + 2) * 32);
            a[pb][1]  = *(const float4*)(pA + (ks + 2) * 32 + 4);
            tt[pb][0] = *(const float4*)(pT + (ks + 2) * 32);
            tt[pb][1] = *(const float4*)(pT + (ks + 2) * 32 + 4);
        }
        if (ks < 3) {
            const unsigned short* pBn = pB + (size_t)(ks + 1) * 4 * NWp * 8;
#pragma unroll
            for (int ti = 0; ti < 7; ++ti)
                curB[ti] = *(const short8*)(pBn + ti * 128);
        }

        accT = __builtin_amdgcn_mfma_f32_16x16x32_bf16(A, T, accT, 0, 0, 0);
#pragma unroll
        for (int ti = 0; ti < 7; ++ti)
            accN[ti] = __builtin_amdgcn_mfma_f32_16x16x32_bf16(A, Bv[ti], accN[ti], 0, 0, 0);
    }

    // ---- combine k-split partials: disjoint slabs, no atomics ----
    float* slab = sAcc + w * 2048;     // slot = tile*256 + reg*64 + lane
#pragma unroll
    for (int ti = 0; ti < 7; ++ti)
#pragma unroll
        for (int r = 0; r < 4; ++r)
            slab[ti * 256 + r * 64 + lane] = accN[ti][r];
#pragma unroll
    for (int r = 0; r < 4; ++r)
        slab[7 * 256 + r * 64 + lane] = accT[r];
    __syncthreads();

    // ---- epilogue: C/D layout col=lane&15, row=(lane>>4)*4+reg ----
    const int ereg = w;
    const int col  = lane & 15;
    const int erow = (lane >> 4) * 4 + ereg;
    float ll = 0.f;
#pragma unroll
    for (int i = 0; i < 7; ++i) {
        int word = i * 16 + col;
        float v = sAcc[i * 256 + t] + sAcc[2048 + i * 256 + t]
                + sAcc[4096 + i * 256 + t] + sAcc[6144 + i * 256 + t];
        if (word < NRn)
            ll += softplus(v + sBn[word]);
    }
    {
        float v = sAcc[7 * 256 + t] + sAcc[2048 + 7 * 256 + t]
                + sAcc[4096 + 7 * 256 + t] + sAcc[6144 + 7 * 256 + t];
        if (col == erow)
            ll += softplus(-(v + sTb[erow]));
    }

#pragma unroll
    for (int off = 32; off > 0; off >>= 1) ll += __shfl_down(ll, off);
    if (lane == 0) sWs[w] = ll;
    __syncthreads();
    if (t == 0) {
        float s = (sWs[0] + sWs[1]) + (sWs[2] + sWs[3]);
        atomicAdd(out, s * (1.f / (float)NROWS));
    }
}

extern "C" void kernel_launch(void* const* d_in, const int* in_sizes, int n_in,
                              void* d_out, int out_size, void* d_ws, size_t ws_size,
                              hipStream_t stream) {
    const float* inp    = (const float*)d_in[0];
    const float* emb    = (const float*)d_in[1];
    const float* bias   = (const float*)d_in[2];
    const float* lpn    = (const float*)d_in[3];
    const int*   target = (const int*)d_in[4];
    const int*   nidx   = (const int*)d_in[5];
    float* out = (float*)d_out;

    unsigned short* nB  = (unsigned short*)d_ws;              // 64*112*8*2 = 114688 B
    float*          nBn = (float*)((char*)d_ws + (size_t)64 * NWp * 8 * 2);

    prep_noise<<<NWp, 128, 0, stream>>>(emb, bias, lpn, nidx, nB, nBn, out);
    nce_loss_kernel<<<NBLK, 256, 0, stream>>>(inp, emb, bias, lpn, target, nB, nBn, out);
}